// Round 6
// baseline (206.571 us; speedup 1.0000x reference)
//
#include <hip/hip_runtime.h>
#include <hip/hip_bf16.h>

#define BB 8
#define SS 4096
#define DD 1024
#define NN 64
#define ROWS (BB * SS)          // 32768
#define GLD 256                 // 4 gates * 64
#define NCHUNK 256              // chunks per sequence
#define CLEN 16                 // steps per chunk (NCHUNK*CLEN == SS)

using bf16x8 = __attribute__((ext_vector_type(8))) short;
using f32x4  = __attribute__((ext_vector_type(4))) float;
typedef unsigned short ushort_t;

__device__ __forceinline__ ushort_t f2b(float f) {
    union { float f; unsigned int u; } v; v.f = f;
    unsigned int u = v.u;
    return (ushort_t)((u + 0x7fffu + ((u >> 16) & 1u)) >> 16);
}
__device__ __forceinline__ float b2f(ushort_t h) {
    union { unsigned int u; float f; } v; v.u = ((unsigned int)h) << 16;
    return v.f;
}

// ---------------- prep A: W' = ln_w ⊙ W packed fragment-linear bf16 hi/lo; Wp -> bf16 ----------------
// pW[s][cb][lane][8] : element = W'[cb*16 + (l&15)][s*32 + (l>>4)*8 + e]
__global__ void prep_pack(const float* __restrict__ Wi, const float* __restrict__ Wf,
                          const float* __restrict__ Wz, const float* __restrict__ Wo,
                          const float* __restrict__ Wp, const float* __restrict__ ln_w,
                          ushort_t* __restrict__ Wph, ushort_t* __restrict__ Wpl,
                          ushort_t* __restrict__ Wpb) {
    int i = blockIdx.x * 256 + threadIdx.x;
    if (i < 32768) {
        int l = i & 63, cb = (i >> 6) & 15, s = i >> 10;
        int r = cb * 16 + (l & 15);
        int c = s * 32 + (l >> 4) * 8;
        int g = r >> 6, rem = r & 63;
        const float* W = (g == 0) ? Wi : (g == 1) ? Wf : (g == 2) ? Wz : Wo;
        const float* src = W + rem * 1024 + c;
        const float* lwp = ln_w + c;
        bf16x8 hi8, lo8;
        #pragma unroll
        for (int e = 0; e < 8; ++e) {
            float w = src[e] * lwp[e];
            ushort_t hb = f2b(w);
            hi8[e] = (short)hb;
            lo8[e] = (short)f2b(w - b2f(hb));
        }
        *reinterpret_cast<bf16x8*>(Wph + (size_t)i * 8) = hi8;
        *reinterpret_cast<bf16x8*>(Wpl + (size_t)i * 8) = lo8;
    } else if (i < 32768 + 65536) {
        int j = i - 32768;
        Wpb[j] = f2b(Wp[j]);
    }
}

// ---------------- prep B: ball[c] = bias_c + Σ ln_b[k] W[c,k];  e_all[c] = Σ ln_w[k] W[c,k] ----------------
// one wave per column, coalesced lanes over k
__global__ __launch_bounds__(256) void prep_bias(const float* __restrict__ Wi, const float* __restrict__ bi,
                                                 const float* __restrict__ Wf, const float* __restrict__ bfv,
                                                 const float* __restrict__ Wz, const float* __restrict__ bz,
                                                 const float* __restrict__ Wo, const float* __restrict__ bo,
                                                 const float* __restrict__ ln_w, const float* __restrict__ ln_b,
                                                 float* __restrict__ ball, float* __restrict__ e_all) {
    int j = blockIdx.x * 4 + (threadIdx.x >> 6);
    int lane = threadIdx.x & 63;
    int g = j >> 6, rem = j & 63;
    const float* W  = (g == 0) ? Wi : (g == 1) ? Wf : (g == 2) ? Wz : Wo;
    const float* bs = (g == 0) ? bi : (g == 1) ? bfv : (g == 2) ? bz : bo;
    const float* row = W + rem * 1024;
    float d = 0.0f, e = 0.0f;
    #pragma unroll
    for (int t = 0; t < 16; ++t) {
        int k = lane + 64 * t;
        float w = row[k];
        e += ln_w[k] * w;
        d += ln_b[k] * w;
    }
    #pragma unroll
    for (int off = 1; off < 64; off <<= 1) {
        e += __shfl_xor(e, off);
        d += __shfl_xor(d, off);
    }
    if (lane == 0) { ball[j] = bs[rem] + d; e_all[j] = e; }
}

// ---------------- fused LN-stats + gate GEMM: full-K LDS tile, ONE barrier ----------------
// block: 256 thr = 4 waves (N split). Tile 16 rows x 256 cols, full K=1024 in LDS (64KB).
// Grid 2048 (2 blocks/CU). No per-step barriers.
__global__ __launch_bounds__(256, 2) void gate_gemm(const float* __restrict__ x,
                                                    const ushort_t* __restrict__ Wph,
                                                    const ushort_t* __restrict__ Wpl,
                                                    const float* __restrict__ ball,
                                                    const float* __restrict__ e_all,
                                                    float* __restrict__ gates) {
    int bm = blockIdx.x * 16;
    int tid = threadIdx.x;
    int wn = tid >> 6, lane = tid & 63;      // wn == gate index
    int lrow = lane & 15, lkg = lane >> 4;
    int srow = tid >> 4, si = tid & 15;      // staging: row (0..15), float4 stripe

    // LDS planes: row-major [16][1024] bf16, 16B-slot XOR swizzle within each 128B seg:
    //   byte(row,col) = row*2048 + (col*2) ^ ((((row&7) ^ ((col>>6)&7))) << 4)
    __shared__ ushort_t lds_h[16][1024];
    __shared__ ushort_t lds_l[16][1024];
    __shared__ float2 stats_lds[16];

    // ---- stage whole x tile (coalesced: lanes 0-15 read 256B contiguous) ----
    const float4* xr = reinterpret_cast<const float4*>(x + (size_t)(bm + srow) * DD);
    float4 arr[16];
    #pragma unroll
    for (int j = 0; j < 16; ++j) arr[j] = xr[si + 16 * j];

    float s1 = 0.0f, s2 = 0.0f;
    char* hbase = (char*)&lds_h[srow][0];
    char* lbase = (char*)&lds_l[srow][0];
    int rm16 = (srow & 7) << 4;
    #pragma unroll
    for (int j = 0; j < 16; ++j) {
        float4 v = arr[j];
        s1 += v.x + v.y + v.z + v.w;
        s2 += v.x * v.x + v.y * v.y + v.z * v.z + v.w * v.w;
        ushort4 hq, lq;
        hq.x = f2b(v.x); lq.x = f2b(v.x - b2f(hq.x));
        hq.y = f2b(v.y); lq.y = f2b(v.y - b2f(hq.y));
        hq.z = f2b(v.z); lq.z = f2b(v.z - b2f(hq.z));
        hq.w = f2b(v.w); lq.w = f2b(v.w - b2f(hq.w));
        int byt = (8 * si + 128 * j) ^ (rm16 ^ ((j & 7) << 4));
        *reinterpret_cast<ushort4*>(hbase + byt) = hq;
        *reinterpret_cast<ushort4*>(lbase + byt) = lq;
    }
    s1 += __shfl_xor(s1, 1); s2 += __shfl_xor(s2, 1);
    s1 += __shfl_xor(s1, 2); s2 += __shfl_xor(s2, 2);
    s1 += __shfl_xor(s1, 4); s2 += __shfl_xor(s2, 4);
    s1 += __shfl_xor(s1, 8); s2 += __shfl_xor(s2, 8);
    if (si == 0) {
        float mu = s1 * (1.0f / DD);
        float var = s2 * (1.0f / DD) - mu * mu;
        float rsd = rsqrtf(var + 1e-5f);
        float2 st; st.x = mu * rsd; st.y = rsd;
        stats_lds[srow] = st;
    }
    __syncthreads();   // the ONLY barrier

    // ---- step loop: LDS reads + register-prefetched W, no barriers ----
    auto loadW = [&](bf16x8 (&w)[4][2], int s) {
        #pragma unroll
        for (int nf = 0; nf < 4; ++nf) {
            size_t base = (((size_t)(s * 16 + wn * 4 + nf)) * 64 + lane) * 8;
            w[nf][0] = *reinterpret_cast<const bf16x8*>(Wph + base);
            w[nf][1] = *reinterpret_cast<const bf16x8*>(Wpl + base);
        }
    };
    f32x4 acc[4] = {};
    const char* hb0 = (const char*)&lds_h[0][0];
    const char* lb0 = (const char*)&lds_l[0][0];
    auto compute = [&](int s, bf16x8 (&w)[4][2]) {
        int seg = s >> 1;
        int e16 = (((s & 1) * 4 + lkg)) << 4;
        int byt = lrow * 2048 + seg * 128 + (e16 ^ ((((lrow & 7) ^ (seg & 7))) << 4));
        bf16x8 ah = *reinterpret_cast<const bf16x8*>(hb0 + byt);
        bf16x8 al = *reinterpret_cast<const bf16x8*>(lb0 + byt);
        #pragma unroll
        for (int nf = 0; nf < 4; ++nf) {
            acc[nf] = __builtin_amdgcn_mfma_f32_16x16x32_bf16(ah, w[nf][0], acc[nf], 0, 0, 0);
            acc[nf] = __builtin_amdgcn_mfma_f32_16x16x32_bf16(ah, w[nf][1], acc[nf], 0, 0, 0);
            acc[nf] = __builtin_amdgcn_mfma_f32_16x16x32_bf16(al, w[nf][0], acc[nf], 0, 0, 0);
        }
    };

    bf16x8 wA[4][2], wB[4][2];
    loadW(wA, 0);
    #pragma unroll 2
    for (int it = 0; it < 16; ++it) {
        loadW(wB, 2 * it + 1);
        compute(2 * it, wA);
        if (it < 15) loadW(wA, 2 * it + 2);
        compute(2 * it + 1, wB);
    }

    // ---- epilogue: LN fold + activations ----
    int c0 = wn * 64;
    int rb = (lane >> 4) * 4;
    #pragma unroll
    for (int nf = 0; nf < 4; ++nf) {
        int col = c0 + nf * 16 + (lane & 15);
        float bc = ball[col];
        float ec = e_all[col];
        #pragma unroll
        for (int r = 0; r < 4; ++r) {
            int rl = rb + r;
            float2 st = stats_lds[rl];
            float v = acc[nf][r] * st.y + bc - st.x * ec;
            float res;
            if (wn == 0 || wn == 1)      res = fminf(fmaxf(v, -20.0f), 20.0f);
            else if (wn == 2)            res = tanhf(v);
            else                         res = 1.0f / (1.0f + expf(-v));
            gates[(size_t)(bm + rl) * GLD + col] = res;
        }
    }
}

// ---------------- scan phase A: per-chunk summaries ----------------
__global__ __launch_bounds__(256) void scan_a(const float* __restrict__ gates,
                                              float* __restrict__ sLf,
                                              float* __restrict__ sM,
                                              float* __restrict__ sC) {
    int w = blockIdx.x * 4 + (threadIdx.x >> 6);
    int lane = threadIdx.x & 63;
    int b = w >> 8, k = w & (NCHUNK - 1);
    int t0 = k * CLEN;
    const float* gp = gates + ((size_t)(b * SS + t0)) * GLD + lane;
    float Lf = 0.0f, m = -1e30f, c = 0.0f;
    for (int t = 0; t < CLEN; ++t) {
        float li = gp[0], lf = gp[64], z = gp[128];
        gp += GLD;
        Lf += lf;
        float ma = m + lf;
        float mn = fmaxf(ma, li);
        c = expf(ma - mn) * c + expf(li - mn) * z;
        m = mn;
    }
    int idx = (b * NCHUNK + k) * 64 + lane;
    sLf[idx] = Lf; sM[idx] = m; sC[idx] = c;
}

// ---------------- scan phase B: sequential compose over chunks (one block per batch) ----------------
__global__ __launch_bounds__(64) void scan_b(const float* __restrict__ sLf,
                                             const float* __restrict__ sM,
                                             const float* __restrict__ sC,
                                             float* __restrict__ cM,
                                             float* __restrict__ cC) {
    int b = blockIdx.x;
    int lane = threadIdx.x;
    float c = 0.0f, m = 0.0f;   // reference init: c0=0, m0=0
    for (int k = 0; k < NCHUNK; ++k) {
        int idx = (b * NCHUNK + k) * 64 + lane;
        cM[idx] = m; cC[idx] = c;
        float Lf = sLf[idx], ml = sM[idx], cl = sC[idx];
        float ma = m + Lf;
        float mo = fmaxf(ma, ml);
        c = expf(ma - mo) * c + expf(ml - mo) * cl;
        m = mo;
    }
}

// ---------------- scan phase C: replay chunks, emit h (bf16) ----------------
__global__ __launch_bounds__(256) void scan_c(const float* __restrict__ gates,
                                              const float* __restrict__ cM,
                                              const float* __restrict__ cC,
                                              ushort_t* __restrict__ h) {
    int w = blockIdx.x * 4 + (threadIdx.x >> 6);
    int lane = threadIdx.x & 63;
    int b = w >> 8, k = w & (NCHUNK - 1);
    int t0 = k * CLEN;
    int idx = (b * NCHUNK + k) * 64 + lane;
    float m = cM[idx], c = cC[idx];
    const float* gp = gates + ((size_t)(b * SS + t0)) * GLD + lane;
    ushort_t* hp = h + ((size_t)(b * SS + t0)) * NN + lane;
    for (int t = 0; t < CLEN; ++t) {
        float li = gp[0], lf = gp[64], z = gp[128], o = gp[192];
        gp += GLD;
        float ma = m + lf;
        float mn = fmaxf(ma, li);
        c = expf(ma - mn) * c + expf(li - mn) * z;
        m = mn;
        *hp = f2b(o * tanhf(c));
        hp += NN;
    }
}

// ---------------- output projection: h(32768x64) * Wpb^T(1024x64) + bp -> out ----------------
__global__ __launch_bounds__(256) void out_gemm(const ushort_t* __restrict__ h,
                                                const ushort_t* __restrict__ Wpb,
                                                const float* __restrict__ bp,
                                                float* __restrict__ out) {
    int tid = threadIdx.x, wid = tid >> 6, lane = tid & 63;
    int r0 = (blockIdx.x >> 1) * 32;
    int c0 = (blockIdx.x & 1) * 512 + wid * 128;
    int lrow = lane & 15, lk = (lane >> 4) * 8;

    f32x4 acc[2][8] = {};
    #pragma unroll
    for (int ks = 0; ks < 2; ++ks) {
        int kk = ks * 32;
        bf16x8 a[2], bfr[8];
        #pragma unroll
        for (int mf = 0; mf < 2; ++mf)
            a[mf] = *reinterpret_cast<const bf16x8*>(h + (size_t)(r0 + mf * 16 + lrow) * NN + kk + lk);
        #pragma unroll
        for (int nf = 0; nf < 8; ++nf)
            bfr[nf] = *reinterpret_cast<const bf16x8*>(Wpb + (size_t)(c0 + nf * 16 + lrow) * NN + kk + lk);
        #pragma unroll
        for (int mf = 0; mf < 2; ++mf)
            #pragma unroll
            for (int nf = 0; nf < 8; ++nf)
                acc[mf][nf] = __builtin_amdgcn_mfma_f32_16x16x32_bf16(a[mf], bfr[nf], acc[mf][nf], 0, 0, 0);
    }
    int rb = (lane >> 4) * 4;
    #pragma unroll
    for (int nf = 0; nf < 8; ++nf) {
        int col = c0 + nf * 16 + (lane & 15);
        float bias = bp[col];
        #pragma unroll
        for (int mf = 0; mf < 2; ++mf) {
            #pragma unroll
            for (int r = 0; r < 4; ++r) {
                int row = r0 + mf * 16 + rb + r;
                out[(size_t)row * DD + col] = acc[mf][nf][r] + bias;
            }
        }
    }
}

extern "C" void kernel_launch(void* const* d_in, const int* in_sizes, int n_in,
                              void* d_out, int out_size, void* d_ws, size_t ws_size,
                              hipStream_t stream) {
    const float* x    = (const float*)d_in[0];
    const float* ln_w = (const float*)d_in[1];
    const float* ln_b = (const float*)d_in[2];
    const float* Wi   = (const float*)d_in[3];
    const float* bi   = (const float*)d_in[4];
    const float* Wf   = (const float*)d_in[5];
    const float* bfv  = (const float*)d_in[6];
    const float* Wz   = (const float*)d_in[7];
    const float* bz   = (const float*)d_in[8];
    const float* Wo   = (const float*)d_in[9];
    const float* bo   = (const float*)d_in[10];
    const float* Wp   = (const float*)d_in[11];
    const float* bp   = (const float*)d_in[12];
    float* out = (float*)d_out;

    // gates fp32 [32768][256] at d_out floats [0, 8.39M)  (33.5 MB; dead before out_gemm)
    float* gates = (float*)d_out;
    // chunk summaries in dead d_out space (floats from 9M; 5 x 131072 floats)
    float* sbase = (float*)d_out + 9 * 1024 * 1024;
    float* sLf = sbase;
    float* sM  = sbase + 1 * (BB * NCHUNK * 64);
    float* sC  = sbase + 2 * (BB * NCHUNK * 64);
    float* cM  = sbase + 3 * (BB * NCHUNK * 64);
    float* cC  = sbase + 4 * (BB * NCHUNK * 64);

    // Small scratch in ws (~5.3 MB)
    char* w = (char*)d_ws;
    ushort_t* h   = (ushort_t*)w; w += (size_t)ROWS * NN * 2;       // 4,194,304
    ushort_t* Wph = (ushort_t*)w; w += 256 * 1024 * 2;              // 524,288
    ushort_t* Wpl = (ushort_t*)w; w += 256 * 1024 * 2;              // 524,288
    ushort_t* Wpb = (ushort_t*)w; w += 1024 * 64 * 2;               // 131,072
    float* ball   = (float*)w;    w += 256 * 4;                     // 1,024
    float* e_all  = (float*)w;    w += 256 * 4;                     // 1,024

    prep_pack<<<384, 256, 0, stream>>>(Wi, Wf, Wz, Wo, Wp, ln_w, Wph, Wpl, Wpb);
    prep_bias<<<64, 256, 0, stream>>>(Wi, bi, Wf, bfv, Wz, bz, Wo, bo, ln_w, ln_b, ball, e_all);
    gate_gemm<<<ROWS / 16, 256, 0, stream>>>(x, Wph, Wpl, ball, e_all, gates);
    scan_a<<<(BB * NCHUNK) / 4, 256, 0, stream>>>(gates, sLf, sM, sC);
    scan_b<<<BB, 64, 0, stream>>>(sLf, sM, sC, cM, cC);
    scan_c<<<(BB * NCHUNK) / 4, 256, 0, stream>>>(gates, cM, cC, h);
    out_gemm<<<(ROWS / 32) * 2, 256, 0, stream>>>(h, Wpb, bp, out);
}

// Round 7
// 173.349 us; speedup vs baseline: 1.1916x; 1.1916x over previous
//
#include <hip/hip_runtime.h>
#include <hip/hip_bf16.h>

#define BB 8
#define SS 4096
#define DD 1024
#define NN 64
#define ROWS (BB * SS)          // 32768
#define GLD 256                 // 4 gates * 64
#define NCHUNK 256              // chunks per sequence
#define CLEN 16                 // steps per chunk (NCHUNK*CLEN == SS)

using bf16x8 = __attribute__((ext_vector_type(8))) short;
using f32x4  = __attribute__((ext_vector_type(4))) float;
typedef unsigned short ushort_t;

__device__ __forceinline__ ushort_t f2b(float f) {
    union { float f; unsigned int u; } v; v.f = f;
    unsigned int u = v.u;
    return (ushort_t)((u + 0x7fffu + ((u >> 16) & 1u)) >> 16);
}
__device__ __forceinline__ float b2f(ushort_t h) {
    union { unsigned int u; float f; } v; v.u = ((unsigned int)h) << 16;
    return v.f;
}

__device__ __forceinline__ void async_copy16(void* lds, const void* g) {
    __builtin_amdgcn_global_load_lds(
        (const __attribute__((address_space(1))) unsigned int*)g,
        (__attribute__((address_space(3))) unsigned int*)lds, 16, 0, 0);
}

// ---------------- prep A: W' = ln_w ⊙ W packed, combined hi/lo slices; Wp -> bf16 ----------------
// Wpk layout: slice s (32 KB = 16384 ushort): [plane(2)][cb(16)][lane(64)][8]
//   element = W'[cb*16 + (l&15)][s*32 + (l>>4)*8 + e]
__global__ void prep_pack(const float* __restrict__ Wi, const float* __restrict__ Wf,
                          const float* __restrict__ Wz, const float* __restrict__ Wo,
                          const float* __restrict__ Wp, const float* __restrict__ ln_w,
                          ushort_t* __restrict__ Wpk, ushort_t* __restrict__ Wpb) {
    int i = blockIdx.x * 256 + threadIdx.x;
    if (i < 32768) {
        int l = i & 63, cb = (i >> 6) & 15, s = i >> 10;
        int r = cb * 16 + (l & 15);
        int c = s * 32 + (l >> 4) * 8;
        int g = r >> 6, rem = r & 63;
        const float* W = (g == 0) ? Wi : (g == 1) ? Wf : (g == 2) ? Wz : Wo;
        const float* src = W + rem * 1024 + c;
        const float* lwp = ln_w + c;
        bf16x8 hi8, lo8;
        #pragma unroll
        for (int e = 0; e < 8; ++e) {
            float w = src[e] * lwp[e];
            ushort_t hb = f2b(w);
            hi8[e] = (short)hb;
            lo8[e] = (short)f2b(w - b2f(hb));
        }
        size_t hiIdx = (size_t)s * 16384 + cb * 512 + l * 8;
        *reinterpret_cast<bf16x8*>(Wpk + hiIdx) = hi8;
        *reinterpret_cast<bf16x8*>(Wpk + hiIdx + 8192) = lo8;
    } else if (i < 32768 + 65536) {
        int j = i - 32768;
        Wpb[j] = f2b(Wp[j]);
    }
}

// ---------------- prep B: ball[c] = bias_c + Σ ln_b[k] W[c,k];  e_all[c] = Σ ln_w[k] W[c,k] ----------------
__global__ __launch_bounds__(256) void prep_bias(const float* __restrict__ Wi, const float* __restrict__ bi,
                                                 const float* __restrict__ Wf, const float* __restrict__ bfv,
                                                 const float* __restrict__ Wz, const float* __restrict__ bz,
                                                 const float* __restrict__ Wo, const float* __restrict__ bo,
                                                 const float* __restrict__ ln_w, const float* __restrict__ ln_b,
                                                 float* __restrict__ ball, float* __restrict__ e_all) {
    int j = blockIdx.x * 4 + (threadIdx.x >> 6);
    int lane = threadIdx.x & 63;
    int g = j >> 6, rem = j & 63;
    const float* W  = (g == 0) ? Wi : (g == 1) ? Wf : (g == 2) ? Wz : Wo;
    const float* bs = (g == 0) ? bi : (g == 1) ? bfv : (g == 2) ? bz : bo;
    const float* row = W + rem * 1024;
    float d = 0.0f, e = 0.0f;
    #pragma unroll
    for (int t = 0; t < 16; ++t) {
        int k = lane + 64 * t;
        float w = row[k];
        e += ln_w[k] * w;
        d += ln_b[k] * w;
    }
    #pragma unroll
    for (int off = 1; off < 64; off <<= 1) {
        e += __shfl_xor(e, off);
        d += __shfl_xor(d, off);
    }
    if (lane == 0) { ball[j] = bs[rem] + d; e_all[j] = e; }
}

// ---------------- fused LN + gate GEMM: m97 structure ----------------
// 512 thr = 8 waves (2M x 4N). Tile 128 x 256, BK=32, 32 K-steps. Grid 256 = 1 block/CU.
// W: global_load_lds double-buffered. x: reg-staged (T14), split to bf16 hi/lo, LN stats
// accumulated during staging (LN folded into W/epilogue).
__global__ __launch_bounds__(512, 1) void gate_gemm(const float* __restrict__ x,
                                                    const ushort_t* __restrict__ Wpk,
                                                    const float* __restrict__ ball,
                                                    const float* __restrict__ e_all,
                                                    float* __restrict__ gates) {
    int bm = blockIdx.x * 128;
    int tid = threadIdx.x;
    int wid = tid >> 6, lane = tid & 63;
    int wm = wid >> 2, wn = wid & 3;     // wn == gate index
    int lrow = lane & 15, lkg = lane >> 4;
    int srow = tid >> 2, skg = tid & 3;  // staging: row 0..127, k-subgroup 0..3

    __shared__ __align__(16) ushort_t Wlds[2][16384];   // 32 KB per buf
    __shared__ __align__(16) ushort_t Xlds[2][8192];    // 16 KB per buf: row-major 128B rows, granule-swizzled
    __shared__ float2 stats_lds[128];

    const float4* xrow = reinterpret_cast<const float4*>(x + (size_t)(bm + srow) * DD) + skg * 2;

    float s1 = 0.0f, s2 = 0.0f;
    float4 xv0, xv1;

    auto loadX = [&](int s) { xv0 = xrow[s * 8]; xv1 = xrow[s * 8 + 1]; };
    auto stageW = [&](int s, int buf) {
        const char* gs = (const char*)Wpk + (size_t)s * 32768 + wid * 4096 + lane * 16;
        char* ls = (char*)&Wlds[buf][0] + wid * 4096;
        #pragma unroll
        for (int i = 0; i < 4; ++i)
            async_copy16(ls + i * 1024, gs + i * 1024);
    };
    auto writeX = [&](int buf) {
        float xv[8] = {xv0.x, xv0.y, xv0.z, xv0.w, xv1.x, xv1.y, xv1.z, xv1.w};
        bf16x8 hi8, lo8;
        #pragma unroll
        for (int e = 0; e < 8; ++e) {
            s1 += xv[e]; s2 += xv[e] * xv[e];
            ushort_t hb = f2b(xv[e]);
            hi8[e] = (short)hb;
            lo8[e] = (short)f2b(xv[e] - b2f(hb));
        }
        char* base = (char*)&Xlds[buf][0] + srow * 128;
        int rm = srow & 7;
        *reinterpret_cast<bf16x8*>(base + 16 * (skg ^ rm)) = hi8;
        *reinterpret_cast<bf16x8*>(base + 16 * ((4 + skg) ^ rm)) = lo8;
    };

    f32x4 acc[4][4] = {};
    auto compute = [&](int buf) {
        bf16x8 ah[4], al[4];
        #pragma unroll
        for (int mf = 0; mf < 4; ++mf) {
            int row = wm * 64 + mf * 16 + lrow;
            const char* b = (const char*)&Xlds[buf][0] + row * 128;
            int rm = row & 7;
            ah[mf] = *reinterpret_cast<const bf16x8*>(b + 16 * (lkg ^ rm));
            al[mf] = *reinterpret_cast<const bf16x8*>(b + 16 * ((4 + lkg) ^ rm));
        }
        #pragma unroll
        for (int nf = 0; nf < 4; ++nf) {
            int cb = wn * 4 + nf;
            const char* wb = (const char*)&Wlds[buf][0];
            bf16x8 bh = *reinterpret_cast<const bf16x8*>(wb + (size_t)(cb * 512 + lane * 8) * 2);
            bf16x8 bl = *reinterpret_cast<const bf16x8*>(wb + (size_t)((16 + cb) * 512 + lane * 8) * 2);
            #pragma unroll
            for (int mf = 0; mf < 4; ++mf) {
                acc[mf][nf] = __builtin_amdgcn_mfma_f32_16x16x32_bf16(ah[mf], bh, acc[mf][nf], 0, 0, 0);
                acc[mf][nf] = __builtin_amdgcn_mfma_f32_16x16x32_bf16(ah[mf], bl, acc[mf][nf], 0, 0, 0);
                acc[mf][nf] = __builtin_amdgcn_mfma_f32_16x16x32_bf16(al[mf], bh, acc[mf][nf], 0, 0, 0);
            }
        }
    };

    // prologue
    loadX(0);
    stageW(0, 0);
    writeX(0);
    __syncthreads();

    for (int s = 0; s < 32; ++s) {
        int buf = s & 1;
        if (s < 31) {
            loadX(s + 1);
            stageW(s + 1, buf ^ 1);
        }
        compute(buf);
        if (s < 31) writeX(buf ^ 1);
        __syncthreads();
    }

    // stats (each row owned by 4 consecutive lanes)
    s1 += __shfl_xor(s1, 1); s2 += __shfl_xor(s2, 1);
    s1 += __shfl_xor(s1, 2); s2 += __shfl_xor(s2, 2);
    if ((tid & 3) == 0) {
        float mu = s1 * (1.0f / DD);
        float var = s2 * (1.0f / DD) - mu * mu;
        float rsd = rsqrtf(var + 1e-5f);
        float2 st; st.x = mu * rsd; st.y = rsd;
        stats_lds[srow] = st;
    }
    __syncthreads();

    // epilogue: LN fold + activations
    int c0 = wn * 64;
    int rb = (lane >> 4) * 4;
    #pragma unroll
    for (int mf = 0; mf < 4; ++mf) {
        #pragma unroll
        for (int nf = 0; nf < 4; ++nf) {
            int col = c0 + nf * 16 + (lane & 15);
            float bc = ball[col];
            float ec = e_all[col];
            #pragma unroll
            for (int r = 0; r < 4; ++r) {
                int rl = wm * 64 + mf * 16 + rb + r;
                float2 st = stats_lds[rl];
                float v = acc[mf][nf][r] * st.y + bc - st.x * ec;
                float res;
                if (wn == 0 || wn == 1)      res = fminf(fmaxf(v, -20.0f), 20.0f);
                else if (wn == 2)            res = tanhf(v);
                else                         res = 1.0f / (1.0f + expf(-v));
                gates[(size_t)(bm + rl) * GLD + col] = res;
            }
        }
    }
}

// ---------------- scan phase A: per-chunk summaries ----------------
__global__ __launch_bounds__(256) void scan_a(const float* __restrict__ gates,
                                              float* __restrict__ sLf,
                                              float* __restrict__ sM,
                                              float* __restrict__ sC) {
    int w = blockIdx.x * 4 + (threadIdx.x >> 6);
    int lane = threadIdx.x & 63;
    int b = w >> 8, k = w & (NCHUNK - 1);
    int t0 = k * CLEN;
    const float* gp = gates + ((size_t)(b * SS + t0)) * GLD + lane;
    float Lf = 0.0f, m = -1e30f, c = 0.0f;
    for (int t = 0; t < CLEN; ++t) {
        float li = gp[0], lf = gp[64], z = gp[128];
        gp += GLD;
        Lf += lf;
        float ma = m + lf;
        float mn = fmaxf(ma, li);
        c = expf(ma - mn) * c + expf(li - mn) * z;
        m = mn;
    }
    int idx = (b * NCHUNK + k) * 64 + lane;
    sLf[idx] = Lf; sM[idx] = m; sC[idx] = c;
}

// ---------------- scan phase B: sequential compose over chunks (one block per batch) ----------------
__global__ __launch_bounds__(64) void scan_b(const float* __restrict__ sLf,
                                             const float* __restrict__ sM,
                                             const float* __restrict__ sC,
                                             float* __restrict__ cM,
                                             float* __restrict__ cC) {
    int b = blockIdx.x;
    int lane = threadIdx.x;
    float c = 0.0f, m = 0.0f;   // reference init: c0=0, m0=0
    for (int k = 0; k < NCHUNK; ++k) {
        int idx = (b * NCHUNK + k) * 64 + lane;
        cM[idx] = m; cC[idx] = c;
        float Lf = sLf[idx], ml = sM[idx], cl = sC[idx];
        float ma = m + Lf;
        float mo = fmaxf(ma, ml);
        c = expf(ma - mo) * c + expf(ml - mo) * cl;
        m = mo;
    }
}

// ---------------- scan phase C: replay chunks, emit h (bf16) ----------------
__global__ __launch_bounds__(256) void scan_c(const float* __restrict__ gates,
                                              const float* __restrict__ cM,
                                              const float* __restrict__ cC,
                                              ushort_t* __restrict__ h) {
    int w = blockIdx.x * 4 + (threadIdx.x >> 6);
    int lane = threadIdx.x & 63;
    int b = w >> 8, k = w & (NCHUNK - 1);
    int t0 = k * CLEN;
    int idx = (b * NCHUNK + k) * 64 + lane;
    float m = cM[idx], c = cC[idx];
    const float* gp = gates + ((size_t)(b * SS + t0)) * GLD + lane;
    ushort_t* hp = h + ((size_t)(b * SS + t0)) * NN + lane;
    for (int t = 0; t < CLEN; ++t) {
        float li = gp[0], lf = gp[64], z = gp[128], o = gp[192];
        gp += GLD;
        float ma = m + lf;
        float mn = fmaxf(ma, li);
        c = expf(ma - mn) * c + expf(li - mn) * z;
        m = mn;
        *hp = f2b(o * tanhf(c));
        hp += NN;
    }
}

// ---------------- output projection: h(32768x64) * Wpb^T(1024x64) + bp -> out ----------------
__global__ __launch_bounds__(256) void out_gemm(const ushort_t* __restrict__ h,
                                                const ushort_t* __restrict__ Wpb,
                                                const float* __restrict__ bp,
                                                float* __restrict__ out) {
    int tid = threadIdx.x, wid = tid >> 6, lane = tid & 63;
    int r0 = (blockIdx.x >> 1) * 32;
    int c0 = (blockIdx.x & 1) * 512 + wid * 128;
    int lrow = lane & 15, lk = (lane >> 4) * 8;

    f32x4 acc[2][8] = {};
    #pragma unroll
    for (int ks = 0; ks < 2; ++ks) {
        int kk = ks * 32;
        bf16x8 a[2], bfr[8];
        #pragma unroll
        for (int mf = 0; mf < 2; ++mf)
            a[mf] = *reinterpret_cast<const bf16x8*>(h + (size_t)(r0 + mf * 16 + lrow) * NN + kk + lk);
        #pragma unroll
        for (int nf = 0; nf < 8; ++nf)
            bfr[nf] = *reinterpret_cast<const bf16x8*>(Wpb + (size_t)(c0 + nf * 16 + lrow) * NN + kk + lk);
        #pragma unroll
        for (int mf = 0; mf < 2; ++mf)
            #pragma unroll
            for (int nf = 0; nf < 8; ++nf)
                acc[mf][nf] = __builtin_amdgcn_mfma_f32_16x16x32_bf16(a[mf], bfr[nf], acc[mf][nf], 0, 0, 0);
    }
    int rb = (lane >> 4) * 4;
    #pragma unroll
    for (int nf = 0; nf < 8; ++nf) {
        int col = c0 + nf * 16 + (lane & 15);
        float bias = bp[col];
        #pragma unroll
        for (int mf = 0; mf < 2; ++mf) {
            #pragma unroll
            for (int r = 0; r < 4; ++r) {
                int row = r0 + mf * 16 + rb + r;
                out[(size_t)row * DD + col] = acc[mf][nf][r] + bias;
            }
        }
    }
}

extern "C" void kernel_launch(void* const* d_in, const int* in_sizes, int n_in,
                              void* d_out, int out_size, void* d_ws, size_t ws_size,
                              hipStream_t stream) {
    const float* x    = (const float*)d_in[0];
    const float* ln_w = (const float*)d_in[1];
    const float* ln_b = (const float*)d_in[2];
    const float* Wi   = (const float*)d_in[3];
    const float* bi   = (const float*)d_in[4];
    const float* Wf   = (const float*)d_in[5];
    const float* bfv  = (const float*)d_in[6];
    const float* Wz   = (const float*)d_in[7];
    const float* bz   = (const float*)d_in[8];
    const float* Wo   = (const float*)d_in[9];
    const float* bo   = (const float*)d_in[10];
    const float* Wp   = (const float*)d_in[11];
    const float* bp   = (const float*)d_in[12];
    float* out = (float*)d_out;

    // gates fp32 [32768][256] at d_out floats [0, 8.39M)  (33.5 MB; dead before out_gemm)
    float* gates = (float*)d_out;
    // chunk summaries in dead d_out space (floats from 9M; 5 x 131072 floats)
    float* sbase = (float*)d_out + 9 * 1024 * 1024;
    float* sLf = sbase;
    float* sM  = sbase + 1 * (BB * NCHUNK * 64);
    float* sC  = sbase + 2 * (BB * NCHUNK * 64);
    float* cM  = sbase + 3 * (BB * NCHUNK * 64);
    float* cC  = sbase + 4 * (BB * NCHUNK * 64);

    // Small scratch in ws (~5.4 MB)
    char* w = (char*)d_ws;
    ushort_t* h   = (ushort_t*)w; w += (size_t)ROWS * NN * 2;       // 4,194,304
    ushort_t* Wpk = (ushort_t*)w; w += 32 * 16384 * 2;              // 1,048,576 (packed hi+lo slices)
    ushort_t* Wpb = (ushort_t*)w; w += 1024 * 64 * 2;               // 131,072
    float* ball   = (float*)w;    w += 256 * 4;                     // 1,024
    float* e_all  = (float*)w;    w += 256 * 4;                     // 1,024

    prep_pack<<<384, 256, 0, stream>>>(Wi, Wf, Wz, Wo, Wp, ln_w, Wpk, Wpb);
    prep_bias<<<64, 256, 0, stream>>>(Wi, bi, Wf, bfv, Wz, bz, Wo, bo, ln_w, ln_b, ball, e_all);
    gate_gemm<<<ROWS / 128, 512, 0, stream>>>(x, Wpk, ball, e_all, gates);
    scan_a<<<(BB * NCHUNK) / 4, 256, 0, stream>>>(gates, sLf, sM, sC);
    scan_b<<<BB, 64, 0, stream>>>(sLf, sM, sC, cM, cC);
    scan_c<<<(BB * NCHUNK) / 4, 256, 0, stream>>>(gates, cM, cC, h);
    out_gemm<<<(ROWS / 32) * 2, 256, 0, stream>>>(h, Wpb, bp, out);
}

// Round 8
// 169.054 us; speedup vs baseline: 1.2219x; 1.0254x over previous
//
#include <hip/hip_runtime.h>
#include <hip/hip_bf16.h>

#define BB 8
#define SS 4096
#define DD 1024
#define NN 64
#define ROWS (BB * SS)          // 32768
#define GLD 256                 // 4 gates * 64
#define NCHUNK 256              // chunks per sequence
#define CLEN 16                 // steps per chunk (NCHUNK*CLEN == SS)

typedef _Float16 f16;
using f16x8 = __attribute__((ext_vector_type(8))) _Float16;
using f32x4 = __attribute__((ext_vector_type(4))) float;

__device__ __forceinline__ void async_copy16(void* lds, const void* g) {
    __builtin_amdgcn_global_load_lds(
        (const __attribute__((address_space(1))) unsigned int*)g,
        (__attribute__((address_space(3))) unsigned int*)lds, 16, 0, 0);
}

// ---------------- prep A: W' = ln_w ⊙ W packed fragment-linear fp16 slices; Wp -> fp16 ----------------
// Wpk layout: slice s (16 KB = 8192 f16): [cb(16)][lane(64)][8]
//   element = W'[cb*16 + (l&15)][s*32 + (l>>4)*8 + e]
__global__ void prep_pack(const float* __restrict__ Wi, const float* __restrict__ Wf,
                          const float* __restrict__ Wz, const float* __restrict__ Wo,
                          const float* __restrict__ Wp, const float* __restrict__ ln_w,
                          f16* __restrict__ Wpk, f16* __restrict__ Wpf) {
    int i = blockIdx.x * 256 + threadIdx.x;
    if (i < 32768) {
        int l = i & 63, cb = (i >> 6) & 15, s = i >> 10;
        int r = cb * 16 + (l & 15);
        int c = s * 32 + (l >> 4) * 8;
        int g = r >> 6, rem = r & 63;
        const float* W = (g == 0) ? Wi : (g == 1) ? Wf : (g == 2) ? Wz : Wo;
        const float* src = W + rem * 1024 + c;
        const float* lwp = ln_w + c;
        f16x8 v;
        #pragma unroll
        for (int e = 0; e < 8; ++e) v[e] = (f16)(src[e] * lwp[e]);
        *reinterpret_cast<f16x8*>(Wpk + (size_t)s * 8192 + cb * 512 + l * 8) = v;
    } else if (i < 32768 + 65536) {
        int j = i - 32768;
        Wpf[j] = (f16)Wp[j];
    }
}

// ---------------- prep B: ball[c] = bias_c + Σ ln_b[k] W[c,k];  e_all[c] = Σ ln_w[k] W[c,k] ----------------
__global__ __launch_bounds__(256) void prep_bias(const float* __restrict__ Wi, const float* __restrict__ bi,
                                                 const float* __restrict__ Wf, const float* __restrict__ bfv,
                                                 const float* __restrict__ Wz, const float* __restrict__ bz,
                                                 const float* __restrict__ Wo, const float* __restrict__ bo,
                                                 const float* __restrict__ ln_w, const float* __restrict__ ln_b,
                                                 float* __restrict__ ball, float* __restrict__ e_all) {
    int j = blockIdx.x * 4 + (threadIdx.x >> 6);
    int lane = threadIdx.x & 63;
    int g = j >> 6, rem = j & 63;
    const float* W  = (g == 0) ? Wi : (g == 1) ? Wf : (g == 2) ? Wz : Wo;
    const float* bs = (g == 0) ? bi : (g == 1) ? bfv : (g == 2) ? bz : bo;
    const float* row = W + rem * 1024;
    float d = 0.0f, e = 0.0f;
    #pragma unroll
    for (int t = 0; t < 16; ++t) {
        int k = lane + 64 * t;
        float w = row[k];
        e += ln_w[k] * w;
        d += ln_b[k] * w;
    }
    #pragma unroll
    for (int off = 1; off < 64; off <<= 1) {
        e += __shfl_xor(e, off);
        d += __shfl_xor(d, off);
    }
    if (lane == 0) { ball[j] = bs[rem] + d; e_all[j] = e; }
}

// ---------------- fused LN + gate GEMM, fp16 single-pass ----------------
// 256 thr = 4 waves (wn = gate). Tile 64 x 256, BK=32, 32 K-steps. Grid 512 = 2 blocks/CU.
// W: global_load_lds double-buffered (16 KB slices). x: reg-staged, cast fp16, LN stats
// accumulated during staging; LN applied via folded epilogue.
__global__ __launch_bounds__(256, 2) void gate_gemm(const float* __restrict__ x,
                                                    const f16* __restrict__ Wpk,
                                                    const float* __restrict__ ball,
                                                    const float* __restrict__ e_all,
                                                    float* __restrict__ gates) {
    int bm = blockIdx.x * 64;
    int tid = threadIdx.x;
    int wn = tid >> 6, lane = tid & 63;      // wn == gate index
    int lrow = lane & 15, lkg = lane >> 4;
    int srow = tid >> 2, skg = tid & 3;      // staging: row 0..63, k-subgroup 0..3

    __shared__ __align__(16) f16 Wlds[2][8192];   // 16 KB per buf
    __shared__ __align__(16) f16 Xlds[2][2048];   // 4 KB per buf: row stride 64 B, 16B-slot swizzle
    __shared__ float2 stats_lds[64];

    const float4* xrow = reinterpret_cast<const float4*>(x + (size_t)(bm + srow) * DD) + skg * 2;

    float s1 = 0.0f, s2 = 0.0f;
    float4 xv0, xv1;

    auto loadX = [&](int s) { xv0 = xrow[s * 8]; xv1 = xrow[s * 8 + 1]; };
    auto stageW = [&](int s, int buf) {
        const char* gs = (const char*)Wpk + (size_t)s * 16384 + wn * 4096 + lane * 16;
        char* ls = (char*)&Wlds[buf][0] + wn * 4096;
        #pragma unroll
        for (int i = 0; i < 4; ++i)
            async_copy16(ls + i * 1024, gs + i * 1024);
    };
    auto writeX = [&](int buf) {
        float xv[8] = {xv0.x, xv0.y, xv0.z, xv0.w, xv1.x, xv1.y, xv1.z, xv1.w};
        f16x8 v;
        #pragma unroll
        for (int e = 0; e < 8; ++e) {
            s1 += xv[e]; s2 += xv[e] * xv[e];
            v[e] = (f16)xv[e];
        }
        char* base = (char*)&Xlds[buf][0] + srow * 64;
        *reinterpret_cast<f16x8*>(base + 16 * (skg ^ (srow & 3))) = v;
    };

    f32x4 acc[4][4] = {};
    auto compute = [&](int buf) {
        f16x8 a[4];
        #pragma unroll
        for (int mf = 0; mf < 4; ++mf) {
            int row = mf * 16 + lrow;
            const char* b = (const char*)&Xlds[buf][0] + row * 64;
            a[mf] = *reinterpret_cast<const f16x8*>(b + 16 * (lkg ^ (row & 3)));
        }
        #pragma unroll
        for (int nf = 0; nf < 4; ++nf) {
            int cb = wn * 4 + nf;
            f16x8 w = *reinterpret_cast<const f16x8*>((const char*)&Wlds[buf][0] + cb * 1024 + lane * 16);
            #pragma unroll
            for (int mf = 0; mf < 4; ++mf)
                acc[mf][nf] = __builtin_amdgcn_mfma_f32_16x16x32_f16(a[mf], w, acc[mf][nf], 0, 0, 0);
        }
    };

    // prologue
    loadX(0);
    stageW(0, 0);
    writeX(0);
    __syncthreads();

    for (int s = 0; s < 32; ++s) {
        int buf = s & 1;
        if (s < 31) {
            loadX(s + 1);
            stageW(s + 1, buf ^ 1);
        }
        compute(buf);
        if (s < 31) writeX(buf ^ 1);
        __syncthreads();
    }

    // stats (each row owned by 4 consecutive threads)
    s1 += __shfl_xor(s1, 1); s2 += __shfl_xor(s2, 1);
    s1 += __shfl_xor(s1, 2); s2 += __shfl_xor(s2, 2);
    if ((tid & 3) == 0) {
        float mu = s1 * (1.0f / DD);
        float var = s2 * (1.0f / DD) - mu * mu;
        float rsd = rsqrtf(var + 1e-5f);
        float2 st; st.x = mu * rsd; st.y = rsd;
        stats_lds[srow] = st;
    }
    __syncthreads();

    // epilogue: LN fold + activations
    int c0 = wn * 64;
    int rb = (lane >> 4) * 4;
    #pragma unroll
    for (int mf = 0; mf < 4; ++mf) {
        #pragma unroll
        for (int nf = 0; nf < 4; ++nf) {
            int col = c0 + nf * 16 + (lane & 15);
            float bc = ball[col];
            float ec = e_all[col];
            #pragma unroll
            for (int r = 0; r < 4; ++r) {
                int rl = mf * 16 + rb + r;
                float2 st = stats_lds[rl];
                float v = acc[mf][nf][r] * st.y + bc - st.x * ec;
                float res;
                if (wn == 0 || wn == 1)      res = fminf(fmaxf(v, -20.0f), 20.0f);
                else if (wn == 2)            res = tanhf(v);
                else                         res = 1.0f / (1.0f + expf(-v));
                gates[(size_t)(bm + rl) * GLD + col] = res;
            }
        }
    }
}

// ---------------- scan phase A: per-chunk summaries ----------------
__global__ __launch_bounds__(256) void scan_a(const float* __restrict__ gates,
                                              float* __restrict__ sLf,
                                              float* __restrict__ sM,
                                              float* __restrict__ sC) {
    int w = blockIdx.x * 4 + (threadIdx.x >> 6);
    int lane = threadIdx.x & 63;
    int b = w >> 8, k = w & (NCHUNK - 1);
    int t0 = k * CLEN;
    const float* gp = gates + ((size_t)(b * SS + t0)) * GLD + lane;
    float Lf = 0.0f, m = -1e30f, c = 0.0f;
    for (int t = 0; t < CLEN; ++t) {
        float li = gp[0], lf = gp[64], z = gp[128];
        gp += GLD;
        Lf += lf;
        float ma = m + lf;
        float mn = fmaxf(ma, li);
        c = expf(ma - mn) * c + expf(li - mn) * z;
        m = mn;
    }
    int idx = (b * NCHUNK + k) * 64 + lane;
    sLf[idx] = Lf; sM[idx] = m; sC[idx] = c;
}

// ---------------- scan phase B: sequential compose over chunks (one block per batch) ----------------
__global__ __launch_bounds__(64) void scan_b(const float* __restrict__ sLf,
                                             const float* __restrict__ sM,
                                             const float* __restrict__ sC,
                                             float* __restrict__ cM,
                                             float* __restrict__ cC) {
    int b = blockIdx.x;
    int lane = threadIdx.x;
    float c = 0.0f, m = 0.0f;   // reference init: c0=0, m0=0
    for (int k = 0; k < NCHUNK; ++k) {
        int idx = (b * NCHUNK + k) * 64 + lane;
        cM[idx] = m; cC[idx] = c;
        float Lf = sLf[idx], ml = sM[idx], cl = sC[idx];
        float ma = m + Lf;
        float mo = fmaxf(ma, ml);
        c = expf(ma - mo) * c + expf(ml - mo) * cl;
        m = mo;
    }
}

// ---------------- scan phase C: replay chunks, emit h (fp16) ----------------
__global__ __launch_bounds__(256) void scan_c(const float* __restrict__ gates,
                                              const float* __restrict__ cM,
                                              const float* __restrict__ cC,
                                              f16* __restrict__ h) {
    int w = blockIdx.x * 4 + (threadIdx.x >> 6);
    int lane = threadIdx.x & 63;
    int b = w >> 8, k = w & (NCHUNK - 1);
    int t0 = k * CLEN;
    int idx = (b * NCHUNK + k) * 64 + lane;
    float m = cM[idx], c = cC[idx];
    const float* gp = gates + ((size_t)(b * SS + t0)) * GLD + lane;
    f16* hp = h + ((size_t)(b * SS + t0)) * NN + lane;
    for (int t = 0; t < CLEN; ++t) {
        float li = gp[0], lf = gp[64], z = gp[128], o = gp[192];
        gp += GLD;
        float ma = m + lf;
        float mn = fmaxf(ma, li);
        c = expf(ma - mn) * c + expf(li - mn) * z;
        m = mn;
        *hp = (f16)(o * tanhf(c));
        hp += NN;
    }
}

// ---------------- output projection: h(32768x64) * Wpf^T(1024x64) + bp -> out ----------------
__global__ __launch_bounds__(256) void out_gemm(const f16* __restrict__ h,
                                                const f16* __restrict__ Wpf,
                                                const float* __restrict__ bp,
                                                float* __restrict__ out) {
    int tid = threadIdx.x, wid = tid >> 6, lane = tid & 63;
    int r0 = (blockIdx.x >> 1) * 32;
    int c0 = (blockIdx.x & 1) * 512 + wid * 128;
    int lrow = lane & 15, lk = (lane >> 4) * 8;

    f32x4 acc[2][8] = {};
    #pragma unroll
    for (int ks = 0; ks < 2; ++ks) {
        int kk = ks * 32;
        f16x8 a[2], bfr[8];
        #pragma unroll
        for (int mf = 0; mf < 2; ++mf)
            a[mf] = *reinterpret_cast<const f16x8*>(h + (size_t)(r0 + mf * 16 + lrow) * NN + kk + lk);
        #pragma unroll
        for (int nf = 0; nf < 8; ++nf)
            bfr[nf] = *reinterpret_cast<const f16x8*>(Wpf + (size_t)(c0 + nf * 16 + lrow) * NN + kk + lk);
        #pragma unroll
        for (int mf = 0; mf < 2; ++mf)
            #pragma unroll
            for (int nf = 0; nf < 8; ++nf)
                acc[mf][nf] = __builtin_amdgcn_mfma_f32_16x16x32_f16(a[mf], bfr[nf], acc[mf][nf], 0, 0, 0);
    }
    int rb = (lane >> 4) * 4;
    #pragma unroll
    for (int nf = 0; nf < 8; ++nf) {
        int col = c0 + nf * 16 + (lane & 15);
        float bias = bp[col];
        #pragma unroll
        for (int mf = 0; mf < 2; ++mf) {
            #pragma unroll
            for (int r = 0; r < 4; ++r) {
                int row = r0 + mf * 16 + rb + r;
                out[(size_t)row * DD + col] = acc[mf][nf][r] + bias;
            }
        }
    }
}

extern "C" void kernel_launch(void* const* d_in, const int* in_sizes, int n_in,
                              void* d_out, int out_size, void* d_ws, size_t ws_size,
                              hipStream_t stream) {
    const float* x    = (const float*)d_in[0];
    const float* ln_w = (const float*)d_in[1];
    const float* ln_b = (const float*)d_in[2];
    const float* Wi   = (const float*)d_in[3];
    const float* bi   = (const float*)d_in[4];
    const float* Wf   = (const float*)d_in[5];
    const float* bfv  = (const float*)d_in[6];
    const float* Wz   = (const float*)d_in[7];
    const float* bz   = (const float*)d_in[8];
    const float* Wo   = (const float*)d_in[9];
    const float* bo   = (const float*)d_in[10];
    const float* Wp   = (const float*)d_in[11];
    const float* bp   = (const float*)d_in[12];
    float* out = (float*)d_out;

    // gates fp32 [32768][256] at d_out floats [0, 8.39M)  (33.5 MB; dead before out_gemm)
    float* gates = (float*)d_out;
    // chunk summaries in dead d_out space (floats from 9M; 5 x 131072 floats)
    float* sbase = (float*)d_out + 9 * 1024 * 1024;
    float* sLf = sbase;
    float* sM  = sbase + 1 * (BB * NCHUNK * 64);
    float* sC  = sbase + 2 * (BB * NCHUNK * 64);
    float* cM  = sbase + 3 * (BB * NCHUNK * 64);
    float* cC  = sbase + 4 * (BB * NCHUNK * 64);

    // Small scratch in ws (~4.9 MB)
    char* w = (char*)d_ws;
    f16* h    = (f16*)w; w += (size_t)ROWS * NN * 2;       // 4,194,304
    f16* Wpk  = (f16*)w; w += 32 * 8192 * 2;               // 524,288 (packed fp16 slices)
    f16* Wpf  = (f16*)w; w += 1024 * 64 * 2;               // 131,072
    float* ball   = (float*)w;    w += 256 * 4;            // 1,024
    float* e_all  = (float*)w;    w += 256 * 4;            // 1,024

    prep_pack<<<384, 256, 0, stream>>>(Wi, Wf, Wz, Wo, Wp, ln_w, Wpk, Wpf);
    prep_bias<<<64, 256, 0, stream>>>(Wi, bi, Wf, bfv, Wz, bz, Wo, bo, ln_w, ln_b, ball, e_all);
    gate_gemm<<<ROWS / 64, 256, 0, stream>>>(x, Wpk, ball, e_all, gates);
    scan_a<<<(BB * NCHUNK) / 4, 256, 0, stream>>>(gates, sLf, sM, sC);
    scan_b<<<BB, 64, 0, stream>>>(sLf, sM, sC, cM, cC);
    scan_c<<<(BB * NCHUNK) / 4, 256, 0, stream>>>(gates, cM, cC, h);
    out_gemm<<<(ROWS / 32) * 2, 256, 0, stream>>>(h, Wpf, bp, out);
}

// Round 9
// 132.878 us; speedup vs baseline: 1.5546x; 1.2722x over previous
//
#include <hip/hip_runtime.h>
#include <hip/hip_bf16.h>

#define BB 8
#define SS 4096
#define DD 1024
#define NN 64
#define ROWS (BB * SS)          // 32768
#define GLD 256                 // 4 gates * 64
#define NCHUNK 256              // chunks per sequence
#define CLEN 16                 // steps per chunk (NCHUNK*CLEN == SS)

typedef _Float16 f16;
using f16x8 = __attribute__((ext_vector_type(8))) _Float16;
using f32x4 = __attribute__((ext_vector_type(4))) float;

// ---------------- prep A: W' = ln_w ⊙ W packed fragment-linear fp16 sub-slices; Wp -> fp16 ----------------
// sub-slice s (16 KB): [cb(16)][lane(64)][8] ; element = W'[cb*16+(l&15)][s*32+(l>>4)*8+e]
// gate_gemm step uses sub-slices {2s, 2s+1} = contiguous 32 KB.
__global__ void prep_pack(const float* __restrict__ Wi, const float* __restrict__ Wf,
                          const float* __restrict__ Wz, const float* __restrict__ Wo,
                          const float* __restrict__ Wp, const float* __restrict__ ln_w,
                          f16* __restrict__ Wpk, f16* __restrict__ Wpf) {
    int i = blockIdx.x * 256 + threadIdx.x;
    if (i < 32768) {
        int l = i & 63, cb = (i >> 6) & 15, s = i >> 10;
        int r = cb * 16 + (l & 15);
        int c = s * 32 + (l >> 4) * 8;
        int g = r >> 6, rem = r & 63;
        const float* W = (g == 0) ? Wi : (g == 1) ? Wf : (g == 2) ? Wz : Wo;
        const float* src = W + rem * 1024 + c;
        const float* lwp = ln_w + c;
        f16x8 v;
        #pragma unroll
        for (int e = 0; e < 8; ++e) v[e] = (f16)(src[e] * lwp[e]);
        *reinterpret_cast<f16x8*>(Wpk + (size_t)s * 8192 + cb * 512 + l * 8) = v;
    } else if (i < 32768 + 65536) {
        int j = i - 32768;
        Wpf[j] = (f16)Wp[j];
    }
}

// ---------------- prep B: ball[c] = bias_c + Σ ln_b[k] W[c,k];  e_all[c] = Σ ln_w[k] W[c,k] ----------------
__global__ __launch_bounds__(256) void prep_bias(const float* __restrict__ Wi, const float* __restrict__ bi,
                                                 const float* __restrict__ Wf, const float* __restrict__ bfv,
                                                 const float* __restrict__ Wz, const float* __restrict__ bz,
                                                 const float* __restrict__ Wo, const float* __restrict__ bo,
                                                 const float* __restrict__ ln_w, const float* __restrict__ ln_b,
                                                 float* __restrict__ ball, float* __restrict__ e_all) {
    int j = blockIdx.x * 4 + (threadIdx.x >> 6);
    int lane = threadIdx.x & 63;
    int g = j >> 6, rem = j & 63;
    const float* W  = (g == 0) ? Wi : (g == 1) ? Wf : (g == 2) ? Wz : Wo;
    const float* bs = (g == 0) ? bi : (g == 1) ? bfv : (g == 2) ? bz : bo;
    const float* row = W + rem * 1024;
    float d = 0.0f, e = 0.0f;
    #pragma unroll
    for (int t = 0; t < 16; ++t) {
        int k = lane + 64 * t;
        float w = row[k];
        e += ln_w[k] * w;
        d += ln_b[k] * w;
    }
    #pragma unroll
    for (int off = 1; off < 64; off <<= 1) {
        e += __shfl_xor(e, off);
        d += __shfl_xor(d, off);
    }
    if (lane == 0) { ball[j] = bs[rem] + d; e_all[j] = e; }
}

// ---------------- fused LN + gate GEMM: raw-barrier deep pipeline ----------------
// 512 thr = 8 waves (2M x 4N). Tile 128 x 256, BK=64, 16 steps. Grid 256 = 1 block/CU.
// x: private regs 2 steps ahead; W: private regs 1 step ahead; both ds_write to dbuf LDS.
// Barriers: lgkmcnt(0) + raw s_barrier (NO vmcnt drain) -> global loads fly across barriers.
__global__ __launch_bounds__(512, 1) void gate_gemm(const float* __restrict__ x,
                                                    const f16* __restrict__ Wpk,
                                                    const float* __restrict__ ball,
                                                    const float* __restrict__ e_all,
                                                    float* __restrict__ gates) {
    int bm = blockIdx.x * 128;
    int tid = threadIdx.x;
    int wid = tid >> 6, lane = tid & 63;
    int wm = wid >> 2, wn = wid & 3;     // wn == gate index
    int lrow = lane & 15, lkg = lane >> 4;
    int srow = tid >> 2, skg = tid & 3;  // x staging: row 0..127, 16-k group

    __shared__ __align__(16) f16 Wlds[2][16384];   // 32 KB per buf
    __shared__ __align__(16) f16 Xlds[2][8192];    // 16 KB per buf: 128 rows x 128 B, slot-XOR swizzle
    __shared__ float2 stats_lds[128];

    // x: thread covers row srow, k-range [s*64 + skg*16, +16) = 4 float4
    const float4* xrow = reinterpret_cast<const float4*>(x + (size_t)(bm + srow) * DD) + skg * 4;
    float4 A0, A1, A2, A3, B0, B1, B2, B3;
    uint4 W0, W1, W2, W3;
    const uint4* wsrc = reinterpret_cast<const uint4*>(Wpk) + wid * 256 + lane;

    auto loadA = [&](int s) { const float4* p = xrow + s * 16; A0 = p[0]; A1 = p[1]; A2 = p[2]; A3 = p[3]; };
    auto loadB = [&](int s) { const float4* p = xrow + s * 16; B0 = p[0]; B1 = p[1]; B2 = p[2]; B3 = p[3]; };
    auto loadW = [&](int s) { const uint4* p = wsrc + (size_t)s * 2048; W0 = p[0]; W1 = p[64]; W2 = p[128]; W3 = p[192]; };
    auto writeW = [&](int buf) {
        uint4* d = reinterpret_cast<uint4*>((char*)&Wlds[buf][0] + wid * 4096) + lane;
        d[0] = W0; d[64] = W1; d[128] = W2; d[192] = W3;
    };

    float s1 = 0.0f, s2 = 0.0f;
    auto writeXv = [&](float4 v0, float4 v1, float4 v2, float4 v3, int buf) {
        float xv[16] = {v0.x, v0.y, v0.z, v0.w, v1.x, v1.y, v1.z, v1.w,
                        v2.x, v2.y, v2.z, v2.w, v3.x, v3.y, v3.z, v3.w};
        f16x8 p0, p1;
        #pragma unroll
        for (int e = 0; e < 8; ++e) {
            s1 += xv[e] + xv[8 + e];
            s2 += xv[e] * xv[e] + xv[8 + e] * xv[8 + e];
            p0[e] = (f16)xv[e];
            p1[e] = (f16)xv[8 + e];
        }
        char* base = (char*)&Xlds[buf][0] + srow * 128;
        int r7 = srow & 7;
        *reinterpret_cast<f16x8*>(base + 16 * ((2 * skg) ^ r7))     = p0;
        *reinterpret_cast<f16x8*>(base + 16 * ((2 * skg + 1) ^ r7)) = p1;
    };

    f32x4 acc[4][4] = {};
    auto compute = [&](int buf) {
        #pragma unroll
        for (int h = 0; h < 2; ++h) {
            f16x8 a[4];
            #pragma unroll
            for (int mf = 0; mf < 4; ++mf) {
                int row = wm * 64 + mf * 16 + lrow;
                a[mf] = *reinterpret_cast<const f16x8*>(
                    (const char*)&Xlds[buf][0] + row * 128 + 16 * ((4 * h + lkg) ^ (row & 7)));
            }
            #pragma unroll
            for (int nf = 0; nf < 4; ++nf) {
                int cb = wn * 4 + nf;
                f16x8 w = *reinterpret_cast<const f16x8*>(
                    (const char*)&Wlds[buf][0] + h * 16384 + cb * 1024 + lane * 16);
                #pragma unroll
                for (int mf = 0; mf < 4; ++mf)
                    acc[mf][nf] = __builtin_amdgcn_mfma_f32_16x16x32_f16(a[mf], w, acc[mf][nf], 0, 0, 0);
            }
        }
    };
    auto stepSync = [&]() {
        asm volatile("s_waitcnt lgkmcnt(0)" ::: "memory");
        __builtin_amdgcn_s_barrier();
        __builtin_amdgcn_sched_barrier(0);
    };

    // prologue: x(0),x(1),W(0) in regs; stage step 0; prefetch x(2), W(1)
    loadA(0); loadB(1); loadW(0);
    writeW(0);
    writeXv(A0, A1, A2, A3, 0);
    loadA(2); loadW(1);
    stepSync();

    for (int it = 0; it < 8; ++it) {
        int s = 2 * it;
        // ---- step s (even, buf0): stage s+1 into buf1 ----
        compute(0);
        writeW(1);                                   // W(s+1)
        writeXv(B0, B1, B2, B3, 1);                  // x(s+1)
        if (s + 2 <= 15) loadW(s + 2);
        if (s + 3 <= 15) loadB(s + 3);
        stepSync();
        // ---- step s+1 (odd, buf1): stage s+2 into buf0 ----
        compute(1);
        if (s + 2 <= 15) {
            writeW(0);                               // W(s+2)
            writeXv(A0, A1, A2, A3, 0);              // x(s+2)
        }
        if (s + 3 <= 15) loadW(s + 3);
        if (s + 4 <= 15) loadA(s + 4);
        stepSync();
    }

    // stats: 4 threads per row
    s1 += __shfl_xor(s1, 1); s2 += __shfl_xor(s2, 1);
    s1 += __shfl_xor(s1, 2); s2 += __shfl_xor(s2, 2);
    if ((tid & 3) == 0) {
        float mu = s1 * (1.0f / DD);
        float var = s2 * (1.0f / DD) - mu * mu;
        float rsd = rsqrtf(var + 1e-5f);
        float2 st; st.x = mu * rsd; st.y = rsd;
        stats_lds[srow] = st;
    }
    __syncthreads();

    // epilogue: LN fold + activations
    int c0 = wn * 64;
    int rb = (lane >> 4) * 4;
    #pragma unroll
    for (int mf = 0; mf < 4; ++mf) {
        #pragma unroll
        for (int nf = 0; nf < 4; ++nf) {
            int col = c0 + nf * 16 + (lane & 15);
            float bc = ball[col];
            float ec = e_all[col];
            #pragma unroll
            for (int r = 0; r < 4; ++r) {
                int rl = wm * 64 + mf * 16 + rb + r;
                float2 st = stats_lds[rl];
                float v = acc[mf][nf][r] * st.y + bc - st.x * ec;
                float res;
                if (wn == 0 || wn == 1)      res = fminf(fmaxf(v, -20.0f), 20.0f);
                else if (wn == 2)            res = tanhf(v);
                else                         res = 1.0f / (1.0f + expf(-v));
                gates[(size_t)(bm + rl) * GLD + col] = res;
            }
        }
    }
}

// ---------------- scan phase A: per-chunk summaries -> interleaved float4 ----------------
__global__ __launch_bounds__(256) void scan_a(const float* __restrict__ gates,
                                              float4* __restrict__ s4) {
    int w = blockIdx.x * 4 + (threadIdx.x >> 6);
    int lane = threadIdx.x & 63;
    int b = w >> 8, k = w & (NCHUNK - 1);
    int t0 = k * CLEN;
    const float* gp = gates + ((size_t)(b * SS + t0)) * GLD + lane;
    float Lf = 0.0f, m = -1e30f, c = 0.0f;
    for (int t = 0; t < CLEN; ++t) {
        float li = gp[0], lf = gp[64], z = gp[128];
        gp += GLD;
        Lf += lf;
        float ma = m + lf;
        float mn = fmaxf(ma, li);
        c = expf(ma - mn) * c + expf(li - mn) * z;
        m = mn;
    }
    float4 v; v.x = Lf; v.y = m; v.z = c; v.w = 0.0f;
    s4[(size_t)(b * NCHUNK + k) * 64 + lane] = v;
}

// ---------------- scan phase B: sequential compose, prefetch-16 pipeline ----------------
__global__ __launch_bounds__(64) void scan_b(const float4* __restrict__ s4,
                                             float2* __restrict__ c2) {
    int b = blockIdx.x;
    int n = threadIdx.x;
    size_t base = (size_t)b * NCHUNK * 64 + n;
    float c = 0.0f, m = 0.0f;   // reference init: c0=0, m0=0
    float4 cur[16];
    #pragma unroll
    for (int d = 0; d < 16; ++d) cur[d] = s4[base + (size_t)d * 64];
    for (int kb = 0; kb < NCHUNK; kb += 16) {
        float4 nxt[16];
        if (kb + 16 < NCHUNK) {
            #pragma unroll
            for (int d = 0; d < 16; ++d) nxt[d] = s4[base + (size_t)(kb + 16 + d) * 64];
        }
        #pragma unroll
        for (int d = 0; d < 16; ++d) {
            float2 ci; ci.x = m; ci.y = c;
            c2[base + (size_t)(kb + d) * 64] = ci;
            float4 v = cur[d];
            float ma = m + v.x;
            float mo = fmaxf(ma, v.y);
            c = expf(ma - mo) * c + expf(v.y - mo) * v.z;
            m = mo;
        }
        #pragma unroll
        for (int d = 0; d < 16; ++d) cur[d] = nxt[d];
    }
}

// ---------------- scan phase C: replay chunks, emit h (fp16) ----------------
__global__ __launch_bounds__(256) void scan_c(const float* __restrict__ gates,
                                              const float2* __restrict__ c2,
                                              f16* __restrict__ h) {
    int w = blockIdx.x * 4 + (threadIdx.x >> 6);
    int lane = threadIdx.x & 63;
    int b = w >> 8, k = w & (NCHUNK - 1);
    int t0 = k * CLEN;
    float2 ci = c2[(size_t)(b * NCHUNK + k) * 64 + lane];
    float m = ci.x, c = ci.y;
    const float* gp = gates + ((size_t)(b * SS + t0)) * GLD + lane;
    f16* hp = h + ((size_t)(b * SS + t0)) * NN + lane;
    for (int t = 0; t < CLEN; ++t) {
        float li = gp[0], lf = gp[64], z = gp[128], o = gp[192];
        gp += GLD;
        float ma = m + lf;
        float mn = fmaxf(ma, li);
        c = expf(ma - mn) * c + expf(li - mn) * z;
        m = mn;
        *hp = (f16)(o * tanhf(c));
        hp += NN;
    }
}

// ---------------- output projection: h(32768x64) * Wpf^T(1024x64) + bp -> out ----------------
__global__ __launch_bounds__(256) void out_gemm(const f16* __restrict__ h,
                                                const f16* __restrict__ Wpf,
                                                const float* __restrict__ bp,
                                                float* __restrict__ out) {
    int tid = threadIdx.x, wid = tid >> 6, lane = tid & 63;
    int r0 = (blockIdx.x >> 1) * 32;
    int c0 = (blockIdx.x & 1) * 512 + wid * 128;
    int lrow = lane & 15, lk = (lane >> 4) * 8;

    f32x4 acc[2][8] = {};
    #pragma unroll
    for (int ks = 0; ks < 2; ++ks) {
        int kk = ks * 32;
        f16x8 a[2], bfr[8];
        #pragma unroll
        for (int mf = 0; mf < 2; ++mf)
            a[mf] = *reinterpret_cast<const f16x8*>(h + (size_t)(r0 + mf * 16 + lrow) * NN + kk + lk);
        #pragma unroll
        for (int nf = 0; nf < 8; ++nf)
            bfr[nf] = *reinterpret_cast<const f16x8*>(Wpf + (size_t)(c0 + nf * 16 + lrow) * NN + kk + lk);
        #pragma unroll
        for (int mf = 0; mf < 2; ++mf)
            #pragma unroll
            for (int nf = 0; nf < 8; ++nf)
                acc[mf][nf] = __builtin_amdgcn_mfma_f32_16x16x32_f16(a[mf], bfr[nf], acc[mf][nf], 0, 0, 0);
    }
    int rb = (lane >> 4) * 4;
    #pragma unroll
    for (int nf = 0; nf < 8; ++nf) {
        int col = c0 + nf * 16 + (lane & 15);
        float bias = bp[col];
        #pragma unroll
        for (int mf = 0; mf < 2; ++mf) {
            #pragma unroll
            for (int r = 0; r < 4; ++r) {
                int row = r0 + mf * 16 + rb + r;
                out[(size_t)row * DD + col] = acc[mf][nf][r] + bias;
            }
        }
    }
}

extern "C" void kernel_launch(void* const* d_in, const int* in_sizes, int n_in,
                              void* d_out, int out_size, void* d_ws, size_t ws_size,
                              hipStream_t stream) {
    const float* x    = (const float*)d_in[0];
    const float* ln_w = (const float*)d_in[1];
    const float* ln_b = (const float*)d_in[2];
    const float* Wi   = (const float*)d_in[3];
    const float* bi   = (const float*)d_in[4];
    const float* Wf   = (const float*)d_in[5];
    const float* bfv  = (const float*)d_in[6];
    const float* Wz   = (const float*)d_in[7];
    const float* bz   = (const float*)d_in[8];
    const float* Wo   = (const float*)d_in[9];
    const float* bo   = (const float*)d_in[10];
    const float* Wp   = (const float*)d_in[11];
    const float* bp   = (const float*)d_in[12];
    float* out = (float*)d_out;

    // gates fp32 [32768][256] at d_out floats [0, 8.39M)  (33.5 MB; dead before out_gemm)
    float* gates = (float*)d_out;
    // chunk summaries in dead d_out space (float offset 9M, 16B aligned):
    //   s4: float4[8*256*64]  (2 MB), c2: float2[8*256*64] (1 MB)
    float4* s4 = (float4*)((float*)d_out + 9 * 1024 * 1024);
    float2* c2 = (float2*)((float*)d_out + 10 * 1024 * 1024);

    // Small scratch in ws (~4.9 MB)
    char* w = (char*)d_ws;
    f16* h    = (f16*)w; w += (size_t)ROWS * NN * 2;       // 4,194,304
    f16* Wpk  = (f16*)w; w += 32 * 8192 * 2;               // 524,288 (packed fp16 sub-slices)
    f16* Wpf  = (f16*)w; w += 1024 * 64 * 2;               // 131,072
    float* ball   = (float*)w;    w += 256 * 4;            // 1,024
    float* e_all  = (float*)w;    w += 256 * 4;            // 1,024

    prep_pack<<<384, 256, 0, stream>>>(Wi, Wf, Wz, Wo, Wp, ln_w, Wpk, Wpf);
    prep_bias<<<64, 256, 0, stream>>>(Wi, bi, Wf, bfv, Wz, bz, Wo, bo, ln_w, ln_b, ball, e_all);
    gate_gemm<<<ROWS / 128, 512, 0, stream>>>(x, Wpk, ball, e_all, gates);
    scan_a<<<(BB * NCHUNK) / 4, 256, 0, stream>>>(gates, s4);
    scan_b<<<BB, 64, 0, stream>>>(s4, c2);
    scan_c<<<(BB * NCHUNK) / 4, 256, 0, stream>>>(gates, c2, h);
    out_gemm<<<(ROWS / 32) * 2, 256, 0, stream>>>(h, Wpf, bp, out);
}